// Round 1
// baseline (12.956 us; speedup 1.0000x reference)
//
#include <hip/hip_runtime.h>
#include <math.h>

// Problem constants (match reference)
#define T_LEN   8192
#define D_DIM   128
#define BLK     128                // outputs per block (= threads per block)
#define NBLK    (T_LEN / BLK)      // 64 blocks
#define GAUSS_C 0.39894228f

// ws float layout:
// [0, T_LEN)               psedu
// [T_LEN, T_LEN+NBLK)      block mins
// [T_LEN+NBLK, T_LEN+2*NBLK) block maxes

__global__ __launch_bounds__(BLK) void k_conv(
    const float* __restrict__ X, const float* __restrict__ weight,
    const float* __restrict__ noise, const float* __restrict__ sigma,
    float* __restrict__ psedu, float* __restrict__ bmin, float* __restrict__ bmax)
{
    __shared__ float wsc[D_DIM];     // softmax(w)_d * C / sigma_d
    __shared__ float inv2[D_DIM];    // 1/(2 sigma_d^2)
    __shared__ float gl2[D_DIM];     // combined taps: gl2[k] = g(63-k), k in [0,128)
    __shared__ float s[BLK + 128];   // spike window (256 values)
    __shared__ float red[4];

    const int tid = threadIdx.x;
    const int t0  = blockIdx.x * BLK;
    const int wv  = tid >> 6;        // wave id (0 or 1)

    // ---- stage spike window: i in [t0-64, t0+192) ----
    #pragma unroll
    for (int li = tid; li < BLK + 128; li += BLK) {
        int i = t0 - 64 + li;
        float x = (i >= 0 && i < T_LEN) ? X[i] : 0.0f;
        s[li] = (x > 0.5f) ? 1.0f : 0.0f;
    }

    // ---- softmax(weight) over D=128 (2 waves) ----
    float w = weight[tid];
    float m = w;
    #pragma unroll
    for (int off = 32; off >= 1; off >>= 1) m = fmaxf(m, __shfl_xor(m, off));
    if ((tid & 63) == 0) red[wv] = m;
    __syncthreads();
    m = fmaxf(red[0], red[1]);
    float e = __expf(w - m);
    float sm = e;
    #pragma unroll
    for (int off = 32; off >= 1; off >>= 1) sm += __shfl_xor(sm, off);
    if ((tid & 63) == 0) red[2 + wv] = sm;
    __syncthreads();
    sm = red[2] + red[3];

    float sg = sigma[tid];
    wsc[tid]  = (e / sm) * (GAUSS_C / sg);
    inv2[tid] = 1.0f / (2.0f * sg * sg);
    __syncthreads();

    // ---- combined kernel taps: rho = 63 - k in [-64, 63] ----
    // exp(-rho^2/(2*sigma^2)) underflows f32 to 0 for |rho| >= 40 (sigma_max=3),
    // so 128 taps reproduce the reference's full 2T-1 kernel exactly (f32).
    {
        float rho = 63.0f - (float)tid;
        float r2  = rho * rho;
        float acc = 0.0f;
        for (int d = 0; d < D_DIM; ++d)
            acc = fmaf(wsc[d], __expf(-r2 * inv2[d]), acc);
        gl2[tid] = acc;
    }
    __syncthreads();

    // ---- 128-tap convolution: psedu[t] = sum_k s[tid+k] * gl2[k] + noise[t] ----
    float a0 = 0.f, a1 = 0.f, a2 = 0.f, a3 = 0.f;
    #pragma unroll
    for (int k = 0; k < 128; k += 4) {
        float4 g4 = *reinterpret_cast<const float4*>(&gl2[k]);   // 16B aligned
        a0 = fmaf(s[tid + k    ], g4.x, a0);
        a1 = fmaf(s[tid + k + 1], g4.y, a1);
        a2 = fmaf(s[tid + k + 2], g4.z, a2);
        a3 = fmaf(s[tid + k + 3], g4.w, a3);
    }
    const int t = t0 + tid;
    float acc = (a0 + a1) + (a2 + a3) + noise[t];
    psedu[t] = acc;

    // ---- block min/max ----
    float mn = acc, mx = acc;
    #pragma unroll
    for (int off = 32; off >= 1; off >>= 1) {
        mn = fminf(mn, __shfl_xor(mn, off));
        mx = fmaxf(mx, __shfl_xor(mx, off));
    }
    __syncthreads();   // red[] reuse: all prior reads done
    if ((tid & 63) == 0) { red[wv] = mn; red[2 + wv] = mx; }
    __syncthreads();
    if (tid == 0) {
        bmin[blockIdx.x] = fminf(red[0], red[1]);
        bmax[blockIdx.x] = fmaxf(red[2], red[3]);
    }
}

__global__ __launch_bounds__(BLK) void k_norm(
    const float* __restrict__ psedu, const float* __restrict__ bmin,
    const float* __restrict__ bmax, float* __restrict__ out)
{
    float gmin = bmin[0], gmax = bmax[0];
    #pragma unroll
    for (int i = 1; i < NBLK; ++i) {
        gmin = fminf(gmin, bmin[i]);
        gmax = fmaxf(gmax, bmax[i]);
    }
    const int t = blockIdx.x * BLK + threadIdx.x;
    out[t] = (psedu[t] - gmin) * (1.0f / (gmax - gmin));
}

extern "C" void kernel_launch(void* const* d_in, const int* in_sizes, int n_in,
                              void* d_out, int out_size, void* d_ws, size_t ws_size,
                              hipStream_t stream) {
    const float* X      = (const float*)d_in[0];   // (1, 8192)
    const float* weight = (const float*)d_in[1];   // (1, 128)
    const float* noise  = (const float*)d_in[2];   // (1, 8192)
    const float* sigma  = (const float*)d_in[3];   // (128,)
    float* out = (float*)d_out;                    // (1, 8192) float32

    float* ws    = (float*)d_ws;
    float* psedu = ws;
    float* bmin  = ws + T_LEN;
    float* bmax  = ws + T_LEN + NBLK;

    k_conv<<<NBLK, BLK, 0, stream>>>(X, weight, noise, sigma, psedu, bmin, bmax);
    k_norm<<<NBLK, BLK, 0, stream>>>(psedu, bmin, bmax, out);
}